// Round 3
// baseline (480.944 us; speedup 1.0000x reference)
//
#include <hip/hip_runtime.h>
#include <hip/hip_bf16.h>

// Problem constants (B,N,HC,HH,K,D) = (64,300,64,64,3,10)
#define BB 64
#define NN 300
#define HH 64
#define RTOT (BB*NN)          // 19200 rows
#define KIO  (3*HH*HH)        // 12288: weights_pool inner size per d
#define JOUT (HH*HH)          // 4096 output cols

typedef __attribute__((ext_vector_type(8))) _Float16 f16x8;
typedef __attribute__((ext_vector_type(4))) float floatx4;

__device__ inline float tanh_fast(float x) {
    float e = __expf(2.f * x);
    return 1.f - 2.f * __builtin_amdgcn_rcpf(e + 1.f);
}

// Fused preprocessing: block-role partitioned single dispatch.
//   [0,300)      adjacency: A[n,:] = softmax(relu(E[n]·E[:]))
//   [300,600)    in_proj: h = relu(z@Win^T + bin), 64-row tiles
//   [600,675)    node_bias: bN = E@bpool
//   [675,1699)   cvt_wout: Wout fp32->fp16
//   [1699,16099) node_weights: Wn[n,kio] = sum_d E[n,d] pool[d,kio]
__global__ __launch_bounds__(256) void k_pre(const float* __restrict__ E,
                                             const float* __restrict__ z,
                                             const float* __restrict__ Win,
                                             const float* __restrict__ bin,
                                             const float* __restrict__ Wout,
                                             const float* __restrict__ pool,
                                             const float* __restrict__ bpool,
                                             float* __restrict__ A,
                                             float* __restrict__ h,
                                             float* __restrict__ Wn,
                                             float* __restrict__ bN,
                                             _Float16* __restrict__ Wh) {
    __shared__ float smem[8576];
    int bid = blockIdx.x, tid = threadIdx.x;

    if (bid < 300) {
        // ---- adjacency ----
        float* sE  = smem;          // 16
        float* row = smem + 16;     // 300
        float* red = smem + 320;    // 256
        int n = bid;
        if (tid < 10) sE[tid] = E[n*10 + tid];
        __syncthreads();
        float lmax = -1e30f;
        for (int m = tid; m < NN; m += 256) {
            float s = 0.f;
            #pragma unroll
            for (int d = 0; d < 10; ++d) s += sE[d] * E[m*10 + d];
            s = fmaxf(s, 0.f);
            row[m] = s;
            lmax = fmaxf(lmax, s);
        }
        red[tid] = lmax; __syncthreads();
        for (int off = 128; off > 0; off >>= 1) {
            if (tid < off) red[tid] = fmaxf(red[tid], red[tid+off]);
            __syncthreads();
        }
        float mx = red[0]; __syncthreads();
        float lsum = 0.f;
        for (int m = tid; m < NN; m += 256) {
            float e = __expf(row[m] - mx);
            row[m] = e;
            lsum += e;
        }
        red[tid] = lsum; __syncthreads();
        for (int off = 128; off > 0; off >>= 1) {
            if (tid < off) red[tid] += red[tid+off];
            __syncthreads();
        }
        float inv = 1.f / red[0];
        for (int m = tid; m < NN; m += 256) A[n*NN + m] = row[m] * inv;
    } else if (bid < 600) {
        // ---- in_proj: 64r x 64o tile ----
        float* Wt = smem;           // 64*68
        float* zl = smem + 4352;    // 64*66
        int tx = tid & 15, ty = tid >> 4;
        int r0 = (bid - 300) * 64;
        for (int e = tid; e < 4096; e += 256) {
            int o = e >> 6, c = e & 63;
            Wt[c*68 + o] = Win[e];
            zl[o*66 + c] = z[(size_t)(r0 + o)*64 + c];
        }
        __syncthreads();
        float4 bo = *(const float4*)&bin[tx*4];
        float acc[4][4];
        #pragma unroll
        for (int s = 0; s < 4; ++s) { acc[s][0]=bo.x; acc[s][1]=bo.y; acc[s][2]=bo.z; acc[s][3]=bo.w; }
        const float* zr = &zl[(ty*4)*66];
        for (int c = 0; c < 64; ++c) {
            float4 w = *(const float4*)&Wt[c*68 + tx*4];
            float z0 = zr[c], z1 = zr[66+c], z2 = zr[132+c], z3 = zr[198+c];
            acc[0][0] += z0*w.x; acc[0][1] += z0*w.y; acc[0][2] += z0*w.z; acc[0][3] += z0*w.w;
            acc[1][0] += z1*w.x; acc[1][1] += z1*w.y; acc[1][2] += z1*w.z; acc[1][3] += z1*w.w;
            acc[2][0] += z2*w.x; acc[2][1] += z2*w.y; acc[2][2] += z2*w.z; acc[2][3] += z2*w.w;
            acc[3][0] += z3*w.x; acc[3][1] += z3*w.y; acc[3][2] += z3*w.z; acc[3][3] += z3*w.w;
        }
        #pragma unroll
        for (int s = 0; s < 4; ++s) {
            float4 v = make_float4(fmaxf(acc[s][0],0.f), fmaxf(acc[s][1],0.f),
                                   fmaxf(acc[s][2],0.f), fmaxf(acc[s][3],0.f));
            *(float4*)&h[(size_t)(r0 + ty*4 + s)*64 + tx*4] = v;
        }
    } else if (bid < 675) {
        // ---- node_bias ----
        int idx = (bid - 600)*256 + tid;   // < 19200
        int n = idx >> 6, o = idx & 63;
        float s = 0.f;
        #pragma unroll
        for (int d = 0; d < 10; ++d) s += E[n*10 + d] * bpool[d*64 + o];
        bN[idx] = s;
    } else if (bid < 1699) {
        // ---- cvt_wout ----
        int idx = (bid - 675)*256 + tid;   // < 262144
        Wh[idx] = (_Float16)Wout[idx];
    } else {
        // ---- node_weights ----
        int idx = (bid - 1699)*256 + tid;  // < 3,686,400
        int n = idx / KIO, kio = idx % KIO;
        float s = 0.f;
        #pragma unroll
        for (int d = 0; d < 10; ++d) s += E[n*10 + d] * pool[d*KIO + kio];
        Wn[idx] = s;
    }
}

// T2 = 2*A@A - I, tiled: block per row n, A[n,:] in LDS, column reads
// coalesced across lanes (m = lane).
__global__ __launch_bounds__(256) void k_cheb(const float* __restrict__ A,
                                              float* __restrict__ T2) {
    __shared__ float Ar[NN];
    int n = blockIdx.x, tid = threadIdx.x;
    for (int m = tid; m < NN; m += 256) Ar[m] = A[n*NN + m];
    __syncthreads();
    for (int m = tid; m < NN; m += 256) {
        float s = 0.f;
        #pragma unroll 4
        for (int l = 0; l < NN; ++l) s += Ar[l] * A[l*NN + m];
        T2[n*NN + m] = 2.f*s - (n == m ? 1.f : 0.f);
    }
}

// One pass: xg1 = A@h, xg2 = T2@h. Wave owns rows r0..r0+4 of BOTH A and
// T2 (10 wave-uniform float4 row streams); each h load feeds 10 FMAs.
// Grid (15, 64).
__global__ __launch_bounds__(256) void k_spatial_both(const float* __restrict__ A,
                                                      const float* __restrict__ T2,
                                                      const float* __restrict__ h,
                                                      float* __restrict__ xg1,
                                                      float* __restrict__ xg2) {
    int tid = threadIdx.x;
    int c = tid & 63;
    int w = __builtin_amdgcn_readfirstlane(tid >> 6);
    int b = blockIdx.y;
    int r0 = blockIdx.x * 20 + w * 5;                  // 0..295
    const float* SA = A  + (size_t)r0 * NN;
    const float* ST = T2 + (size_t)r0 * NN;
    const float* hb = h + (size_t)b * NN * 64 + c;
    float accA[5] = {0.f,0.f,0.f,0.f,0.f};
    float accT[5] = {0.f,0.f,0.f,0.f,0.f};
    for (int m = 0; m < NN; m += 4) {
        float4 sa[5], st[5];
        #pragma unroll
        for (int i = 0; i < 5; ++i) {
            sa[i] = *(const float4*)(SA + i*NN + m);
            st[i] = *(const float4*)(ST + i*NN + m);
        }
        float h0 = hb[(m+0)*64];
        float h1 = hb[(m+1)*64];
        float h2 = hb[(m+2)*64];
        float h3 = hb[(m+3)*64];
        #pragma unroll
        for (int i = 0; i < 5; ++i) {
            accA[i] = fmaf(sa[i].x,h0,accA[i]); accA[i] = fmaf(sa[i].y,h1,accA[i]);
            accA[i] = fmaf(sa[i].z,h2,accA[i]); accA[i] = fmaf(sa[i].w,h3,accA[i]);
            accT[i] = fmaf(st[i].x,h0,accT[i]); accT[i] = fmaf(st[i].y,h1,accT[i]);
            accT[i] = fmaf(st[i].z,h2,accT[i]); accT[i] = fmaf(st[i].w,h3,accT[i]);
        }
    }
    float* d1 = xg1 + ((size_t)b * NN + r0) * 64 + c;
    float* d2 = xg2 + ((size_t)b * NN + r0) * 64 + c;
    #pragma unroll
    for (int i = 0; i < 5; ++i) {
        d1[i*64] = accA[i];
        d2[i*64] = accT[i];
    }
}

// h2[b,n,o] = bN[n,o] + sum_{ki} xg[b,n,ki] * Wn[n,ki,o]; k=0 slice = h.
// Block = (n, half of b): 32 b-lanes, 8 half-wave o-chunks of 8.
// xgl transposed with XOR swizzle: addr(ki,b) = ki*32 + (b ^ (ki&31)) --
// bijective, conflict-free on BOTH the ki-varying write and b-varying read.
// Wn panel read 2x total (was 8x). LDS 72 KB -> 2 blocks/CU.
__global__ __launch_bounds__(256) void k_node_mm(const float* __restrict__ h,
                                                 const float* __restrict__ xg1,
                                                 const float* __restrict__ xg2,
                                                 const float* __restrict__ Wn,
                                                 const float* __restrict__ bN,
                                                 _Float16* __restrict__ h2h) {
    __shared__ float Wnl[12288];    // 48 KB, [ki*64 + o]
    __shared__ float xgl[6144];     // 24 KB, swizzled [ki][b^(ki&31)]
    int tid = threadIdx.x;
    int n = blockIdx.x, b_base = blockIdx.y * 32;

    // Wn panel -> LDS (float4, coalesced)
    const float4* Wsrc = (const float4*)(Wn + (size_t)n*KIO);
    for (int e4 = tid; e4 < 3072; e4 += 256) ((float4*)Wnl)[e4] = Wsrc[e4];

    // xg (k=0:h, 1:xg1, 2:xg2) -> swizzled LDS. 1536 float4s.
    for (int e4 = tid; e4 < 1536; e4 += 256) {
        int gi = e4 * 4;            // float index
        int bl = gi / 192, kb = gi % 192;      // kb multiple of 4, no k-cross
        int k = kb >> 6, i = kb & 63;
        const float* src = (k == 0) ? h : ((k == 1) ? xg1 : xg2);
        float4 v = *(const float4*)&src[((size_t)(b_base + bl)*NN + n)*64 + i];
        xgl[(kb+0)*32 + (bl ^ ((kb+0)&31))] = v.x;
        xgl[(kb+1)*32 + (bl ^ ((kb+1)&31))] = v.y;
        xgl[(kb+2)*32 + (bl ^ ((kb+2)&31))] = v.z;
        xgl[(kb+3)*32 + (bl ^ ((kb+3)&31))] = v.w;
    }
    __syncthreads();

    int bl = tid & 31;              // lane -> b
    int o0 = (tid >> 5) * 8;        // half-wave -> o-chunk
    float acc[8];
    #pragma unroll
    for (int j = 0; j < 8; ++j) acc[j] = bN[n*64 + o0 + j];

    for (int ki = 0; ki < 192; ++ki) {
        float x = xgl[ki*32 + (bl ^ (ki & 31))];
        float4 w0 = *(const float4*)&Wnl[ki*64 + o0];
        float4 w1 = *(const float4*)&Wnl[ki*64 + o0 + 4];
        acc[0] = fmaf(x, w0.x, acc[0]); acc[1] = fmaf(x, w0.y, acc[1]);
        acc[2] = fmaf(x, w0.z, acc[2]); acc[3] = fmaf(x, w0.w, acc[3]);
        acc[4] = fmaf(x, w1.x, acc[4]); acc[5] = fmaf(x, w1.y, acc[5]);
        acc[6] = fmaf(x, w1.z, acc[6]); acc[7] = fmaf(x, w1.w, acc[7]);
    }
    f16x8 v;
    #pragma unroll
    for (int j = 0; j < 8; ++j) v[j] = (_Float16)acc[j];
    *(f16x8*)&h2h[((size_t)(b_base + bl)*NN + n)*64 + o0] = v;
}

// out[r,j] = tanh( h2[r,:]·Wout[j,:] + bout[j] ), fp16 MFMA 16x16x32.
// Non-temporal stores: 315 MB write-once stream must not displace
// the L2-resident h2h/Wh tiles.
__global__ __launch_bounds__(256) void k_out_proj_mfma(const _Float16* __restrict__ h2h,
                                                       const _Float16* __restrict__ Wh,
                                                       const float* __restrict__ bout,
                                                       float* __restrict__ out) {
    int tid  = threadIdx.x;
    int wave = tid >> 6, lane = tid & 63;
    int quad = lane >> 4, lr = lane & 15;
    int m0 = blockIdx.y*128 + (wave >> 1)*64;
    int n0 = blockIdx.x*128 + (wave & 1)*64;
    floatx4 acc[4][4] = {};   // [m-frag][n-frag]
    const _Float16* Aptr = h2h + (size_t)(m0 + lr)*64 + quad*8;
    const _Float16* Bptr = Wh  + (size_t)(n0 + lr)*64 + quad*8;
    #pragma unroll
    for (int ks = 0; ks < 2; ++ks) {
        f16x8 a[4], b[4];
        #pragma unroll
        for (int f = 0; f < 4; ++f) {
            a[f] = *(const f16x8*)(Aptr + (size_t)f*16*64 + ks*32);
            b[f] = *(const f16x8*)(Bptr + (size_t)f*16*64 + ks*32);
        }
        #pragma unroll
        for (int mf = 0; mf < 4; ++mf)
            #pragma unroll
            for (int nf = 0; nf < 4; ++nf)
                acc[mf][nf] = __builtin_amdgcn_mfma_f32_16x16x32_f16(a[mf], b[nf], acc[mf][nf], 0, 0, 0);
    }
    // C/D layout: col = lane&15, row = quad*4 + reg  [m89-verified, dtype-indep]
    #pragma unroll
    for (int nf = 0; nf < 4; ++nf) {
        int col = n0 + nf*16 + lr;
        float bj = bout[col];
        #pragma unroll
        for (int mf = 0; mf < 4; ++mf) {
            int row = m0 + mf*16 + quad*4;
            #pragma unroll
            for (int r = 0; r < 4; ++r) {
                float v = tanh_fast(acc[mf][nf][r] + bj);
                __builtin_nontemporal_store(v, &out[(size_t)(row + r)*JOUT + col]);
            }
        }
    }
}

extern "C" void kernel_launch(void* const* d_in, const int* in_sizes, int n_in,
                              void* d_out, int out_size, void* d_ws, size_t ws_size,
                              hipStream_t stream) {
    const float* z     = (const float*)d_in[0];   // [64,300,64]
    const float* Win   = (const float*)d_in[1];   // [64,64]
    const float* bin   = (const float*)d_in[2];   // [64]
    const float* Wout  = (const float*)d_in[3];   // [4096,64]
    const float* bout  = (const float*)d_in[4];   // [4096]
    const float* E     = (const float*)d_in[5];   // [300,10]
    const float* pool  = (const float*)d_in[6];   // [10,3,64,64]
    const float* bpool = (const float*)d_in[7];   // [10,64]
    float* out = (float*)d_out;                   // [64,300,64,64]

    float* ws  = (float*)d_ws;
    float* A   = ws;                 // 90,000
    float* T2  = A   + 90000;        // 90,000
    float* Wn  = T2  + 90000;        // 3,686,400
    float* bN  = Wn  + 3686400;      // 19,200
    float* h   = bN  + 19200;        // 1,228,800
    float* xg1 = h   + 1228800;      // 1,228,800
    float* xg2 = xg1 + 1228800;      // 1,228,800
    _Float16* h2h   = (_Float16*)(xg2 + 1228800); // 1,228,800 fp16
    _Float16* Wouth = h2h + 1228800;              // 262,144 fp16 (total ~33.6 MB)

    k_pre         <<<16099, 256, 0, stream>>>(E, z, Win, bin, Wout, pool, bpool,
                                              A, h, Wn, bN, Wouth);
    k_cheb        <<<NN, 256, 0, stream>>>(A, T2);
    k_spatial_both<<<dim3(15, BB), 256, 0, stream>>>(A, T2, h, xg1, xg2);
    k_node_mm     <<<dim3(NN, 2), 256, 0, stream>>>(h, xg1, xg2, Wn, bN, h2h);
    k_out_proj_mfma<<<dim3(JOUT/128, RTOT/128), 256, 0, stream>>>(h2h, Wouth, bout, out);
}

// Round 4
// 449.251 us; speedup vs baseline: 1.0705x; 1.0705x over previous
//
#include <hip/hip_runtime.h>
#include <hip/hip_bf16.h>

// Problem constants (B,N,HC,HH,K,D) = (64,300,64,64,3,10)
#define BB 64
#define NN 300
#define HH 64
#define RTOT (BB*NN)          // 19200 rows
#define KIO  (3*HH*HH)        // 12288: weights_pool inner size per d
#define JOUT (HH*HH)          // 4096 output cols

typedef __attribute__((ext_vector_type(8))) _Float16 f16x8;
typedef __attribute__((ext_vector_type(4))) float floatx4;

__device__ inline float tanh_fast(float x) {
    float e = __expf(2.f * x);
    return 1.f - 2.f * __builtin_amdgcn_rcpf(e + 1.f);
}

// Fused preprocessing: block-role partitioned single dispatch.
//   [0,300)      adjacency: A[n,:] = softmax(relu(E[n]·E[:]))
//   [300,600)    in_proj: h = relu(z@Win^T + bin), 64-row tiles
//   [600,675)    node_bias: bN = E@bpool
//   [675,1699)   cvt_wout: Wout fp32->fp16
//   [1699,16099) node_weights: Wn[n,kio] = sum_d E[n,d] pool[d,kio]
__global__ __launch_bounds__(256) void k_pre(const float* __restrict__ E,
                                             const float* __restrict__ z,
                                             const float* __restrict__ Win,
                                             const float* __restrict__ bin,
                                             const float* __restrict__ Wout,
                                             const float* __restrict__ pool,
                                             const float* __restrict__ bpool,
                                             float* __restrict__ A,
                                             float* __restrict__ h,
                                             float* __restrict__ Wn,
                                             float* __restrict__ bN,
                                             _Float16* __restrict__ Wh) {
    __shared__ float smem[8576];
    int bid = blockIdx.x, tid = threadIdx.x;

    if (bid < 300) {
        // ---- adjacency ----
        float* sE  = smem;          // 16
        float* row = smem + 16;     // 300
        float* red = smem + 320;    // 256
        int n = bid;
        if (tid < 10) sE[tid] = E[n*10 + tid];
        __syncthreads();
        float lmax = -1e30f;
        for (int m = tid; m < NN; m += 256) {
            float s = 0.f;
            #pragma unroll
            for (int d = 0; d < 10; ++d) s += sE[d] * E[m*10 + d];
            s = fmaxf(s, 0.f);
            row[m] = s;
            lmax = fmaxf(lmax, s);
        }
        red[tid] = lmax; __syncthreads();
        for (int off = 128; off > 0; off >>= 1) {
            if (tid < off) red[tid] = fmaxf(red[tid], red[tid+off]);
            __syncthreads();
        }
        float mx = red[0]; __syncthreads();
        float lsum = 0.f;
        for (int m = tid; m < NN; m += 256) {
            float e = __expf(row[m] - mx);
            row[m] = e;
            lsum += e;
        }
        red[tid] = lsum; __syncthreads();
        for (int off = 128; off > 0; off >>= 1) {
            if (tid < off) red[tid] += red[tid+off];
            __syncthreads();
        }
        float inv = 1.f / red[0];
        for (int m = tid; m < NN; m += 256) A[n*NN + m] = row[m] * inv;
    } else if (bid < 600) {
        // ---- in_proj: 64r x 64o tile ----
        float* Wt = smem;           // 64*68
        float* zl = smem + 4352;    // 64*66
        int tx = tid & 15, ty = tid >> 4;
        int r0 = (bid - 300) * 64;
        for (int e = tid; e < 4096; e += 256) {
            int o = e >> 6, c = e & 63;
            Wt[c*68 + o] = Win[e];
            zl[o*66 + c] = z[(size_t)(r0 + o)*64 + c];
        }
        __syncthreads();
        float4 bo = *(const float4*)&bin[tx*4];
        float acc[4][4];
        #pragma unroll
        for (int s = 0; s < 4; ++s) { acc[s][0]=bo.x; acc[s][1]=bo.y; acc[s][2]=bo.z; acc[s][3]=bo.w; }
        const float* zr = &zl[(ty*4)*66];
        for (int c = 0; c < 64; ++c) {
            float4 w = *(const float4*)&Wt[c*68 + tx*4];
            float z0 = zr[c], z1 = zr[66+c], z2 = zr[132+c], z3 = zr[198+c];
            acc[0][0] += z0*w.x; acc[0][1] += z0*w.y; acc[0][2] += z0*w.z; acc[0][3] += z0*w.w;
            acc[1][0] += z1*w.x; acc[1][1] += z1*w.y; acc[1][2] += z1*w.z; acc[1][3] += z1*w.w;
            acc[2][0] += z2*w.x; acc[2][1] += z2*w.y; acc[2][2] += z2*w.z; acc[2][3] += z2*w.w;
            acc[3][0] += z3*w.x; acc[3][1] += z3*w.y; acc[3][2] += z3*w.z; acc[3][3] += z3*w.w;
        }
        #pragma unroll
        for (int s = 0; s < 4; ++s) {
            float4 v = make_float4(fmaxf(acc[s][0],0.f), fmaxf(acc[s][1],0.f),
                                   fmaxf(acc[s][2],0.f), fmaxf(acc[s][3],0.f));
            *(float4*)&h[(size_t)(r0 + ty*4 + s)*64 + tx*4] = v;
        }
    } else if (bid < 675) {
        // ---- node_bias ----
        int idx = (bid - 600)*256 + tid;   // < 19200
        int n = idx >> 6, o = idx & 63;
        float s = 0.f;
        #pragma unroll
        for (int d = 0; d < 10; ++d) s += E[n*10 + d] * bpool[d*64 + o];
        bN[idx] = s;
    } else if (bid < 1699) {
        // ---- cvt_wout ----
        int idx = (bid - 675)*256 + tid;   // < 262144
        Wh[idx] = (_Float16)Wout[idx];
    } else {
        // ---- node_weights ----
        int idx = (bid - 1699)*256 + tid;  // < 3,686,400
        int n = idx / KIO, kio = idx % KIO;
        float s = 0.f;
        #pragma unroll
        for (int d = 0; d < 10; ++d) s += E[n*10 + d] * pool[d*KIO + kio];
        Wn[idx] = s;
    }
}

// xg1[b,r,c] = sum_m A[r,m] h[b,m,c].
// Wave owns 5 rows of A for one b; lane = channel c. A chunks are
// wave-uniform float4 loads; each h load feeds 5 FMAs. Grid (15, 64).
__global__ __launch_bounds__(256) void k_spatialA(const float* __restrict__ A,
                                                  const float* __restrict__ h,
                                                  float* __restrict__ xg1) {
    int tid = threadIdx.x;
    int c = tid & 63;
    int w = __builtin_amdgcn_readfirstlane(tid >> 6);
    int b = blockIdx.y;
    int r0 = blockIdx.x * 20 + w * 5;                  // 0..295
    const float* S = A + (size_t)r0 * NN;
    const float* hb = h + (size_t)b * NN * 64 + c;
    float a0 = 0.f, a1 = 0.f, a2 = 0.f, a3 = 0.f, a4 = 0.f;
    for (int m = 0; m < NN; m += 4) {
        float4 s0 = *(const float4*)(S + 0*NN + m);
        float4 s1 = *(const float4*)(S + 1*NN + m);
        float4 s2 = *(const float4*)(S + 2*NN + m);
        float4 s3 = *(const float4*)(S + 3*NN + m);
        float4 s4 = *(const float4*)(S + 4*NN + m);
        float h0 = hb[(m+0)*64];
        float h1 = hb[(m+1)*64];
        float h2 = hb[(m+2)*64];
        float h3 = hb[(m+3)*64];
        a0 = fmaf(s0.x,h0,a0); a0 = fmaf(s0.y,h1,a0); a0 = fmaf(s0.z,h2,a0); a0 = fmaf(s0.w,h3,a0);
        a1 = fmaf(s1.x,h0,a1); a1 = fmaf(s1.y,h1,a1); a1 = fmaf(s1.z,h2,a1); a1 = fmaf(s1.w,h3,a1);
        a2 = fmaf(s2.x,h0,a2); a2 = fmaf(s2.y,h1,a2); a2 = fmaf(s2.z,h2,a2); a2 = fmaf(s2.w,h3,a2);
        a3 = fmaf(s3.x,h0,a3); a3 = fmaf(s3.y,h1,a3); a3 = fmaf(s3.z,h2,a3); a3 = fmaf(s3.w,h3,a3);
        a4 = fmaf(s4.x,h0,a4); a4 = fmaf(s4.y,h1,a4); a4 = fmaf(s4.z,h2,a4); a4 = fmaf(s4.w,h3,a4);
    }
    float* dst = xg1 + ((size_t)b * NN + r0) * 64 + c;
    dst[0*64] = a0; dst[1*64] = a1; dst[2*64] = a2; dst[3*64] = a3; dst[4*64] = a4;
}

// Chebyshev on features: xg2 = T2@h = (2A^2 - I)h = 2*A@xg1 - h
__global__ __launch_bounds__(256) void k_spatialB(const float* __restrict__ A,
                                                  const float* __restrict__ xg1,
                                                  const float* __restrict__ h,
                                                  float* __restrict__ xg2) {
    int tid = threadIdx.x;
    int c = tid & 63;
    int w = __builtin_amdgcn_readfirstlane(tid >> 6);
    int b = blockIdx.y;
    int r0 = blockIdx.x * 20 + w * 5;
    const float* S = A + (size_t)r0 * NN;
    const float* xb = xg1 + (size_t)b * NN * 64 + c;
    float a0 = 0.f, a1 = 0.f, a2 = 0.f, a3 = 0.f, a4 = 0.f;
    for (int m = 0; m < NN; m += 4) {
        float4 s0 = *(const float4*)(S + 0*NN + m);
        float4 s1 = *(const float4*)(S + 1*NN + m);
        float4 s2 = *(const float4*)(S + 2*NN + m);
        float4 s3 = *(const float4*)(S + 3*NN + m);
        float4 s4 = *(const float4*)(S + 4*NN + m);
        float x0 = xb[(m+0)*64];
        float x1 = xb[(m+1)*64];
        float x2 = xb[(m+2)*64];
        float x3 = xb[(m+3)*64];
        a0 = fmaf(s0.x,x0,a0); a0 = fmaf(s0.y,x1,a0); a0 = fmaf(s0.z,x2,a0); a0 = fmaf(s0.w,x3,a0);
        a1 = fmaf(s1.x,x0,a1); a1 = fmaf(s1.y,x1,a1); a1 = fmaf(s1.z,x2,a1); a1 = fmaf(s1.w,x3,a1);
        a2 = fmaf(s2.x,x0,a2); a2 = fmaf(s2.y,x1,a2); a2 = fmaf(s2.z,x2,a2); a2 = fmaf(s2.w,x3,a2);
        a3 = fmaf(s3.x,x0,a3); a3 = fmaf(s3.y,x1,a3); a3 = fmaf(s3.z,x2,a3); a3 = fmaf(s3.w,x3,a3);
        a4 = fmaf(s4.x,x0,a4); a4 = fmaf(s4.y,x1,a4); a4 = fmaf(s4.z,x2,a4); a4 = fmaf(s4.w,x3,a4);
    }
    const float* hb = h   + ((size_t)b * NN + r0) * 64 + c;
    float*       dst = xg2 + ((size_t)b * NN + r0) * 64 + c;
    dst[0*64] = 2.f*a0 - hb[0*64];
    dst[1*64] = 2.f*a1 - hb[1*64];
    dst[2*64] = 2.f*a2 - hb[2*64];
    dst[3*64] = 2.f*a3 - hb[3*64];
    dst[4*64] = 2.f*a4 - hb[4*64];
}

// h2[b,n,o] = bN[n,o] + sum_{ki} xg[b,n,ki] * Wn[n,ki,o]; k=0 slice = h.
// R1-proven structure (grid 300x8); inner loop ki-unrolled x4 with
// float4 broadcast reads of xgl (1 ds_read_b128 + 4 b32 + 4 FMA per 4 ki).
__global__ __launch_bounds__(256) void k_node_mm(const float* __restrict__ h,
                                                 const float* __restrict__ xg1,
                                                 const float* __restrict__ xg2,
                                                 const float* __restrict__ Wn,
                                                 const float* __restrict__ bN,
                                                 _Float16* __restrict__ h2h) {
    __shared__ float Wnl[192*64];   // 48 KB
    __shared__ float xgl[8][192];
    int tid = threadIdx.x;
    int o = tid & 63, ty = tid >> 6;
    int n = blockIdx.x, b0 = blockIdx.y*8;
    for (int e = tid; e < 12288; e += 256) Wnl[e] = Wn[(size_t)n*KIO + e];
    for (int e = tid; e < 8*192; e += 256) {
        int bb = e / 192, ki = e % 192;
        int k = ki >> 6, i = ki & 63;
        const float* src = (k == 0) ? h : ((k == 1) ? xg1 : xg2);
        xgl[bb][ki] = src[((b0+bb)*NN + n)*64 + i];
    }
    __syncthreads();
    float bias = bN[n*64 + o];
    for (int bb = ty; bb < 8; bb += 4) {
        float acc = bias;
        for (int ki = 0; ki < 192; ki += 4) {
            float4 x4 = *(const float4*)&xgl[bb][ki];
            float w0 = Wnl[(ki+0)*64 + o];
            float w1 = Wnl[(ki+1)*64 + o];
            float w2 = Wnl[(ki+2)*64 + o];
            float w3 = Wnl[(ki+3)*64 + o];
            acc = fmaf(x4.x, w0, acc); acc = fmaf(x4.y, w1, acc);
            acc = fmaf(x4.z, w2, acc); acc = fmaf(x4.w, w3, acc);
        }
        h2h[((b0+bb)*NN + n)*64 + o] = (_Float16)acc;
    }
}

// out[r,j] = tanh( h2[r,:]·Wout[j,:] + bout[j] ), fp16 MFMA 16x16x32.
// SWAPPED operand order: mfma(b, a) puts out-row on lane&15 and out-col
// on quad*4+reg -> each lane owns 4 consecutive cols -> float4 NT stores
// (16 dwordx4 per thread instead of 64 scalar stores).
__global__ __launch_bounds__(256) void k_out_proj_mfma(const _Float16* __restrict__ h2h,
                                                       const _Float16* __restrict__ Wh,
                                                       const float* __restrict__ bout,
                                                       float* __restrict__ out) {
    int tid  = threadIdx.x;
    int wave = tid >> 6, lane = tid & 63;
    int quad = lane >> 4, lr = lane & 15;
    int m0 = blockIdx.y*128 + (wave >> 1)*64;
    int n0 = blockIdx.x*128 + (wave & 1)*64;
    floatx4 acc[4][4] = {};   // [m-frag][n-frag]
    const _Float16* Aptr = h2h + (size_t)(m0 + lr)*64 + quad*8;
    const _Float16* Bptr = Wh  + (size_t)(n0 + lr)*64 + quad*8;
    #pragma unroll
    for (int ks = 0; ks < 2; ++ks) {
        f16x8 a[4], b[4];
        #pragma unroll
        for (int f = 0; f < 4; ++f) {
            a[f] = *(const f16x8*)(Aptr + (size_t)f*16*64 + ks*32);
            b[f] = *(const f16x8*)(Bptr + (size_t)f*16*64 + ks*32);
        }
        #pragma unroll
        for (int mf = 0; mf < 4; ++mf)
            #pragma unroll
            for (int nf = 0; nf < 4; ++nf)
                acc[mf][nf] = __builtin_amdgcn_mfma_f32_16x16x32_f16(b[nf], a[mf], acc[mf][nf], 0, 0, 0);
    }
    // Swapped D layout: lane&15 -> h2h row (out row), quad*4+reg -> Wh row (out col)
    #pragma unroll
    for (int nf = 0; nf < 4; ++nf) {
        int c0 = n0 + nf*16 + quad*4;
        float4 bj = *(const float4*)&bout[c0];
        #pragma unroll
        for (int mf = 0; mf < 4; ++mf) {
            int row = m0 + mf*16 + lr;
            floatx4 v;
            v[0] = tanh_fast(acc[mf][nf][0] + bj.x);
            v[1] = tanh_fast(acc[mf][nf][1] + bj.y);
            v[2] = tanh_fast(acc[mf][nf][2] + bj.z);
            v[3] = tanh_fast(acc[mf][nf][3] + bj.w);
            __builtin_nontemporal_store(v, (floatx4*)&out[(size_t)row*JOUT + c0]);
        }
    }
}

extern "C" void kernel_launch(void* const* d_in, const int* in_sizes, int n_in,
                              void* d_out, int out_size, void* d_ws, size_t ws_size,
                              hipStream_t stream) {
    const float* z     = (const float*)d_in[0];   // [64,300,64]
    const float* Win   = (const float*)d_in[1];   // [64,64]
    const float* bin   = (const float*)d_in[2];   // [64]
    const float* Wout  = (const float*)d_in[3];   // [4096,64]
    const float* bout  = (const float*)d_in[4];   // [4096]
    const float* E     = (const float*)d_in[5];   // [300,10]
    const float* pool  = (const float*)d_in[6];   // [10,3,64,64]
    const float* bpool = (const float*)d_in[7];   // [10,64]
    float* out = (float*)d_out;                   // [64,300,64,64]

    float* ws  = (float*)d_ws;
    float* A   = ws;                 // 90,000
    float* Wn  = A   + 90000;        // 3,686,400
    float* bN  = Wn  + 3686400;      // 19,200
    float* h   = bN  + 19200;        // 1,228,800
    float* xg1 = h   + 1228800;      // 1,228,800
    float* xg2 = xg1 + 1228800;      // 1,228,800
    _Float16* h2h   = (_Float16*)(xg2 + 1228800); // 1,228,800 fp16
    _Float16* Wouth = h2h + 1228800;              // 262,144 fp16 (total ~33 MB)

    k_pre      <<<16099, 256, 0, stream>>>(E, z, Win, bin, Wout, pool, bpool,
                                           A, h, Wn, bN, Wouth);
    k_spatialA <<<dim3(15, BB), 256, 0, stream>>>(A, h, xg1);
    k_spatialB <<<dim3(15, BB), 256, 0, stream>>>(A, xg1, h, xg2);
    k_node_mm  <<<dim3(NN, 8), 256, 0, stream>>>(h, xg1, xg2, Wn, bN, h2h);
    k_out_proj_mfma<<<dim3(JOUT/128, RTOT/128), 256, 0, stream>>>(h2h, Wouth, bout, out);
}